// Round 3
// baseline (218.671 us; speedup 1.0000x reference)
//
#include <hip/hip_runtime.h>
#include <math.h>

#define B_ 2
#define N_ 2048
#define E_ 1024
#define H_ 16
#define D_ 64

typedef unsigned short US;
typedef _Float16 h16x8 __attribute__((ext_vector_type(8)));
typedef _Float16 h16x4 __attribute__((ext_vector_type(4)));
typedef __fp16 fp16x2 __attribute__((ext_vector_type(2)));
typedef float f32x4 __attribute__((ext_vector_type(4)));
#define MFMA16F(a,b,c)  __builtin_amdgcn_mfma_f32_16x16x32_f16(a,b,c,0,0,0)
#define MFMA161(a,b,c)  __builtin_amdgcn_mfma_f32_16x16x16f16(a,b,c,0,0,0)
#define SCL  11.5415603828f   // 8 * log2(e), folded into Q at the QKV-GEMM epilogue

union HU { _Float16 h; US u; };
__device__ __forceinline__ US f2h(float f){ HU x; x.h = (_Float16)f; return x.u; }
__device__ __forceinline__ unsigned pkrtz(float a, float b){
  union { fp16x2 h; unsigned u; } x;
  x.h = __builtin_amdgcn_cvt_pkrtz(a, b);
  return x.u;
}

union U8 { US u[8]; uint4 v; };
union U4 { US u[4]; uint2 v; };
union UPA { unsigned u[2]; h16x4 h; };

// async global->LDS, 16B/lane; LDS dest = wave-uniform base + lane*16 (no padding possible)
__device__ __forceinline__ void glds16(const US* g, US* l){
  __builtin_amdgcn_global_load_lds(
    (const __attribute__((address_space(1))) unsigned int*)(const void*)g,
    (__attribute__((address_space(3))) unsigned int*)(void*)l, 16, 0, 0);
}

// ---- fused convert: x (2048 blocks) + Wq/Wk/Wv/Wo (512 blocks each) fp32->fp16 ----
__global__ __launch_bounds__(256) void conv_all(
    const float* __restrict__ x,
    const float* __restrict__ w0, const float* __restrict__ w1,
    const float* __restrict__ w2, const float* __restrict__ w3,
    US* __restrict__ xh, US* __restrict__ Wall)
{
  const int id = blockIdx.x;
  const float* s; US* d; size_t off;
  if (id < 2048) { s = x; d = xh; off = (size_t)id*2048; }
  else {
    int j = id - 2048, wsel = j>>9;
    off = (size_t)(j&511)*2048;
    s = (wsel==0)?w0:(wsel==1)?w1:(wsel==2)?w2:w3;
    d = Wall + (size_t)wsel*1048576;
  }
  size_t i = off + (size_t)threadIdx.x*8;
  float f[8];
  *(float4*)&f[0] = *(const float4*)&s[i];
  *(float4*)&f[4] = *(const float4*)&s[i+4];
  U8 h;
  #pragma unroll
  for (int j=0;j<8;++j) h.u[j] = f2h(f[j]);
  *(uint4*)&d[i] = h.v;
}

// ---- QKV GEMM, m97 geometry: 128x128 tile, BK=32, z-sliced (z selects Wq/Wk/Wv).
// Grid (8,32,3) = 768 blocks = exactly 3 blocks/CU at (256,3) -> single occupancy round.
// Outputs: z=0 Q*SCL fp16 [B,H,N,D]; z=1 K fp16 [B,H,N,D]; z=2 V fp16 [B,H,D,N] (transposed).
__global__ __launch_bounds__(256,3) void qkv_gemm(
    const US* __restrict__ A, const US* __restrict__ Wall,
    const float* __restrict__ bq, const float* __restrict__ bk, const float* __restrict__ bv,
    US* __restrict__ Qf, US* __restrict__ Kf, US* __restrict__ Vtb)
{
  __shared__ __align__(16) US sA[128*32];
  __shared__ __align__(16) US sW[128*32];
  const int z = blockIdx.z;
  const US* W = Wall + (size_t)z*1048576;
  const float* bias = (z==0)?bq:(z==1)?bk:bv;

  const int t = threadIdx.x;
  const int w = t>>6, lane = t&63;
  const int q = lane>>4, c = lane&15;
  const int mq = (w>>1)*64, nq = (w&1)*64;
  const int gm0 = blockIdx.y*128, gn0 = blockIdx.x*128;
  const int r16 = lane>>2, seg = lane&3;    // staging: 4 lanes/row, 16B each

  f32x4 acc[4][4] = {};
  for (int kb = 0; kb < 1024; kb += 32) {
    #pragma unroll
    for (int p=0;p<2;++p){
      int rb = (w*2+p)*16;
      glds16(&A[(size_t)(gm0 + rb + r16)*1024 + kb + seg*8], &sA[rb*32]);
      glds16(&W[(size_t)(gn0 + rb + r16)*1024 + kb + seg*8], &sW[rb*32]);
    }
    __syncthreads();
    h16x8 af[4], wf[4];
    #pragma unroll
    for (int rt=0;rt<4;++rt) af[rt] = *(const h16x8*)&sA[(mq+rt*16+c)*32 + q*8];
    #pragma unroll
    for (int ct=0;ct<4;++ct) wf[ct] = *(const h16x8*)&sW[(nq+ct*16+c)*32 + q*8];
    #pragma unroll
    for (int rt=0;rt<4;++rt)
      #pragma unroll
      for (int ct=0;ct<4;++ct)
        acc[rt][ct] = MFMA16F(af[rt], wf[ct], acc[rt][ct]);
    __syncthreads();
  }
  #pragma unroll
  for (int rt=0;rt<4;++rt)
  #pragma unroll
  for (int ct=0;ct<4;++ct) {
    int col = gn0 + nq + ct*16 + c;
    float bv_ = bias[col];
    int rowb = gm0 + mq + rt*16 + q*4;
    int hh = col>>6, d = col & 63;
    if (z==2) {
      int b = rowb>>11, n = rowb & (N_-1);
      U4 pk;
      #pragma unroll
      for (int r=0;r<4;++r) pk.u[r] = f2h(acc[rt][ct][r] + bv_);
      *(uint2*)&Vtb[((size_t)(b*H_+hh)*D_ + d)*N_ + n] = pk.v;
    } else {
      US* dst = (z==0) ? Qf : Kf;
      #pragma unroll
      for (int r=0;r<4;++r) {
        int row = rowb + r;
        float v = acc[rt][ct][r] + bv_;
        if (z==0) v *= SCL;      // fold softmax scale + log2e into Q (fp32, pre-rounding)
        int b = row>>11, n = row & (N_-1);
        dst[((size_t)(b*H_+hh)*N_+n)*D_ + d] = f2h(v);
      }
    }
  }
}

// ---- O GEMM: out = H @ Wo^T + bo, fp32 row-major [4096][1024].
// 128M x 64N, BK=32; grid 16x32 = 512 = 2 blocks/CU at (256,4): single round.
__global__ __launch_bounds__(256,4) void o_gemm(
    const US* __restrict__ A, const US* __restrict__ W,
    const float* __restrict__ bias, float* __restrict__ out)
{
  __shared__ __align__(16) US sA[128*32];
  __shared__ __align__(16) US sW[64*32];
  const int t = threadIdx.x;
  const int w = t>>6, lane = t&63;
  const int q = lane>>4, c = lane&15;
  const int gm0 = blockIdx.y*128, gn0 = blockIdx.x*64;
  const int r16 = lane>>2, seg = lane&3;

  f32x4 acc[2][4] = {};
  for (int kb = 0; kb < 1024; kb += 32) {
    glds16(&A[(size_t)(gm0 + w*32      + r16)*1024 + kb + seg*8], &sA[(w*32)*32]);
    glds16(&A[(size_t)(gm0 + w*32 + 16 + r16)*1024 + kb + seg*8], &sA[(w*32+16)*32]);
    glds16(&W[(size_t)(gn0 + w*16      + r16)*1024 + kb + seg*8], &sW[(w*16)*32]);
    __syncthreads();
    h16x8 af0 = *(const h16x8*)&sA[(w*32+c)*32 + q*8];
    h16x8 af1 = *(const h16x8*)&sA[(w*32+16+c)*32 + q*8];
    #pragma unroll
    for (int ct=0; ct<4; ++ct){
      h16x8 wf = *(const h16x8*)&sW[(ct*16+c)*32 + q*8];
      acc[0][ct] = MFMA16F(af0, wf, acc[0][ct]);
      acc[1][ct] = MFMA16F(af1, wf, acc[1][ct]);
    }
    __syncthreads();
  }
  #pragma unroll
  for (int rt=0; rt<2; ++rt)
  #pragma unroll
  for (int ct=0; ct<4; ++ct) {
    int col = gn0 + ct*16 + c;
    float bv_ = bias[col];
    int rowb = gm0 + w*32 + rt*16 + q*4;
    #pragma unroll
    for (int r=0;r<4;++r)
      out[(size_t)(rowb+r)*1024 + col] = acc[rt][ct][r] + bv_;
  }
}

// ---- Flash attention, R12: software-pipelined QK (T15-lite).
// Register insight: s[8] (32 regs) is dead once exp2 packs it into pa_ (16 regs), so
// QK(t+1) refills s IN THE SAME post-barrier region as PV(t): one 56-MFMA cluster with
// no VALU on its critical path. Softmax(t) moves BEFORE the barrier where it covers the
// async staging latency (T14 role, zero staging regs).
// Staging is glds16 (async global->LDS). Linear-dest constraint -> XOR swizzle with
// pre-swizzled GLOBAL source + swizzled READ (rule #21, both-sides-or-neither):
//   K: LDS[r][ch8]  = K[r][ch8 ^ (r&7)]   (128B rows, 8 16B-chunks)
//   V: LDS[r][ch16] = V[r][ch16 ^ (r&15)] (256B rows, 16 16B-chunks)
// Both read patterns stay bank-uniform (8 accesses/bank = the 1KB minimum).
// Schedule per iter t: [glds(t+1)->buf^1][softmax(t): s->pa_][barrier B, drains vmcnt]
//                      [QK(t+1)->s || PV(t) from pa_][barrier A].
// Defer-max THR=8 (exp2 domain): skip rescale while tile max <= mi+8; P <= 2^8 is
// fp16-safe; relative precision unchanged (l-normalization absorbs the scale).
// VGPR ~100 < 128 -> 16 waves/CU retained. LDS 64 KB (2 blocks/CU, grid-capped).
__global__ __launch_bounds__(512,4) void attn(
    const US* __restrict__ Qf, const US* __restrict__ Kf, const US* __restrict__ Vt,
    US* __restrict__ Hout)
{
  __shared__ __align__(16) US sK [2][128*64];
  __shared__ __align__(16) US sVt[2][64*128];
  const int t = threadIdx.x;
  const int w = t>>6, lane = t&63, q = lane>>4, c = lane&15;
  const int id = blockIdx.x;
  // XCD swizzle: 16 q-tiles of one (b,h) stay on one XCD (id%8 stable across them)
  const int bh = ((id & 7) << 2) | ((id >> 3) & 3);
  const int n0 = (id >> 5) * 128;
  const US* Kp = Kf + (size_t)bh * (N_*D_);
  const US* Vp = Vt + (size_t)bh * (D_*N_);

  // Q B-frags in registers (pre-scaled): rows n0 + w*16 + c
  const size_t qoff = (size_t)bh*(N_*D_) + (size_t)(n0 + w*16 + c)*D_;
  h16x8 qb0 = *(const h16x8*)&Qf[qoff + q*8];
  h16x8 qb1 = *(const h16x8*)&Qf[qoff + 32 + q*8];
  h16x4 vones;
  #pragma unroll
  for (int j=0;j<4;++j) vones[j] = (_Float16)1.0f;

  float mi = -INFINITY;
  f32x4 o[5] = {};           // 0..3 = output d-cols; 4 = l accumulator (ones-row)

  // staging geometry: per wave, K chunks {2w,2w+1} (8 rows/chunk), V chunks {2w,2w+1} (4 rows/chunk)
  const int klr = lane>>3, klc = lane&7;     // K: row-in-chunk, 16B-chunk-in-row
  const int vlr = lane>>4, vlc = lane&15;    // V: row-in-chunk, 16B-chunk-in-row

  #define STAGE(MT, BUF)                                                              \
    { const int m0_ = (MT)*128;                                                       \
      _Pragma("unroll")                                                               \
      for (int p=0;p<2;++p){                                                          \
        int ch = 2*w + p;                                                             \
        int row = ch*8 + klr;                                                         \
        glds16(&Kp[(size_t)(m0_+row)*D_ + ((klc ^ (row&7))<<3)], &sK[BUF][ch<<9]);    \
      }                                                                               \
      _Pragma("unroll")                                                               \
      for (int p=0;p<2;++p){                                                          \
        int ch = 2*w + p;                                                             \
        int row = ch*4 + vlr;                                                         \
        glds16(&Vp[(size_t)row*N_ + m0_ + ((vlc ^ (row&15))<<3)], &sVt[BUF][ch<<9]);  \
      }                                                                               \
    }

  // prologue: stage tile 0 -> buf0; compute QK(0)
  STAGE(0, 0);
  __syncthreads();
  f32x4 s[8];
  #pragma unroll
  for (int f=0; f<8; ++f){
    int r8 = (f*16+c)*64;
    h16x8 k0 = *(const h16x8*)&sK[0][r8 + (( q      ^ (c&7))<<3)];
    h16x8 k1 = *(const h16x8*)&sK[0][r8 + (((q+4)   ^ (c&7))<<3)];
    f32x4 sv = {};
    sv = MFMA16F(k0, qb0, sv);
    sv = MFMA16F(k1, qb1, sv);
    s[f] = sv;
  }

  for (int mt=0; mt<16; ++mt) {
    const int cur = mt&1;
    if (mt < 15) STAGE(mt+1, cur^1);

    // ---- softmax(mt): s -> pa_ (pre-barrier; covers glds latency) ----
    // row-max: max3-friendly grouping, keys lane-local (32/lane); this lane's qrow = c
    f32x4 t1, t2;
    #pragma unroll
    for (int j=0;j<4;++j){
      float a = fmaxf(fmaxf(s[0][j],s[1][j]),s[2][j]);
      float b = fmaxf(fmaxf(s[3][j],s[4][j]),s[5][j]);
      float d = fmaxf(fmaxf(s[6][j],s[7][j]),a);
      t1[j] = fmaxf(b,d);
    }
    float v = fmaxf(fmaxf(t1[0],t1[1]), fmaxf(t1[2],t1[3]));
    v = fmaxf(v, __shfl_xor(v, 16));
    v = fmaxf(v, __shfl_xor(v, 32));     // replicated across the 4 q-lanes
    // defer-max: rescale only when some row exceeds mi by >8 (P <= 2^8 fp16-safe)
    if (!__all(v <= mi + 8.0f)) {
      float mnew = fmaxf(mi, v);
      float alpha = exp2f(mi - mnew);
      float ar[4];
      #pragma unroll
      for (int r=0; r<4; ++r) ar[r] = __shfl(alpha, q*4+r);
      #pragma unroll
      for (int dt=0; dt<5; ++dt){        // includes the l accumulator
        o[dt][0]*=ar[0]; o[dt][1]*=ar[1]; o[dt][2]*=ar[2]; o[dt][3]*=ar[3];
      }
      mi = mnew;
    }
    UPA pa_[8];
    #pragma unroll
    for (int f=0; f<8; ++f){
      float p0 = exp2f(s[f][0]-mi);
      float p1 = exp2f(s[f][1]-mi);
      float p2 = exp2f(s[f][2]-mi);
      float p3 = exp2f(s[f][3]-mi);
      pa_[f].u[0] = pkrtz(p0, p1);
      pa_[f].u[1] = pkrtz(p2, p3);
    }

    __syncthreads();   // B: glds(t+1) drained (compiler emits vmcnt(0) before s_barrier)

    // ---- merged MFMA region: QK(mt+1) refills s  ||  PV(mt) consumes pa_ ----
    __builtin_amdgcn_s_setprio(1);
    if (mt < 15){
      #pragma unroll
      for (int f=0; f<8; ++f){
        int r8 = (f*16+c)*64;
        h16x8 k0 = *(const h16x8*)&sK[cur^1][r8 + (( q    ^ (c&7))<<3)];
        h16x8 k1 = *(const h16x8*)&sK[cur^1][r8 + (((q+4) ^ (c&7))<<3)];
        f32x4 sv = {};
        sv = MFMA16F(k0, qb0, sv);
        sv = MFMA16F(k1, qb1, sv);
        s[f] = sv;
      }
    }
    #pragma unroll
    for (int f=0; f<8; ++f){
      h16x4 pah = pa_[f].h;
      #pragma unroll
      for (int dt=0; dt<4; ++dt){
        // V read with both-sides swizzle: chunk16 = (2f + (q>>1)) ^ c, +8B when q odd
        h16x4 vf = *(const h16x4*)&sVt[cur][(dt*16+c)*128 + ((((f<<1)+(q>>1)) ^ c)<<3) + ((q&1)<<2)];
        o[dt] = MFMA161(pah, vf, o[dt]);
      }
      o[4] = MFMA161(pah, vones, o[4]);
    }
    __builtin_amdgcn_s_setprio(0);
    __syncthreads();   // A: protects buf[cur] V from next iter's glds writes
  }
  #undef STAGE

  // l is row-indexed (component r = row q*4+r): no shfl needed
  const int b = bh>>4, hh = bh&15;
  float ir[4];
  #pragma unroll
  for (int r=0; r<4; ++r) ir[r] = 1.0f / o[4][r];
  #pragma unroll
  for (int dt=0; dt<4; ++dt){
    #pragma unroll
    for (int r=0; r<4; ++r){
      int n = n0 + w*16 + q*4 + r;
      int d = dt*16 + c;
      Hout[((size_t)(b*N_+n)*H_+hh)*D_ + d] = f2h(o[dt][r] * ir[r]);  // [B,N,E] fp16
    }
  }
}

extern "C" void kernel_launch(void* const* d_in, const int* in_sizes, int n_in,
                              void* d_out, int out_size, void* d_ws, size_t ws_size,
                              hipStream_t stream)
{
  const float* x  = (const float*)d_in[0];
  const float* Wq = (const float*)d_in[1];
  const float* bq = (const float*)d_in[2];
  const float* Wk = (const float*)d_in[3];
  const float* bk = (const float*)d_in[4];
  const float* Wv = (const float*)d_in[5];
  const float* bv = (const float*)d_in[6];
  const float* Wo = (const float*)d_in[7];
  const float* bo = (const float*)d_in[8];
  US* ws  = (US*)d_ws;
  const size_t M1 = 1048576;
  US* xh   = ws;                 // 4M fp16
  US* Wall = ws + 4*M1;          // 4M: Wq,Wk,Wv,Wo fp16 contiguous
  US* Qf   = ws + 8*M1;          // 4M, [B,H,N,D], pre-scaled by 8*log2e
  US* Kf   = ws + 12*M1;         // 4M, [B,H,N,D]
  US* Vtb  = ws + 16*M1;         // 4M, [B,H,D,N]
  US* Hf   = ws + 20*M1;         // 4M, [B,N,E]  -> 48 MB total

  conv_all<<<4096, 256, 0, stream>>>(x, Wq, Wk, Wv, Wo, xh, Wall);
  qkv_gemm<<<dim3(8,32,3), 256, 0, stream>>>(xh, Wall, bq, bk, bv, Qf, Kf, Vtb);
  attn<<<512, 512, 0, stream>>>(Qf, Kf, Vtb, Hf);
  o_gemm<<<dim3(16,32), 256, 0, stream>>>(Hf, Wall + 3*M1, bo, (float*)d_out);
}

// Round 4
// 204.345 us; speedup vs baseline: 1.0701x; 1.0701x over previous
//
#include <hip/hip_runtime.h>
#include <math.h>

#define B_ 2
#define N_ 2048
#define E_ 1024
#define H_ 16
#define D_ 64

typedef unsigned short US;
typedef _Float16 h16x8 __attribute__((ext_vector_type(8)));
typedef _Float16 h16x4 __attribute__((ext_vector_type(4)));
typedef __fp16 fp16x2 __attribute__((ext_vector_type(2)));
typedef float f32x4 __attribute__((ext_vector_type(4)));
#define MFMA16F(a,b,c)  __builtin_amdgcn_mfma_f32_16x16x32_f16(a,b,c,0,0,0)
#define MFMA161(a,b,c)  __builtin_amdgcn_mfma_f32_16x16x16f16(a,b,c,0,0,0)
#define SCL  11.5415603828f   // 8 * log2(e), folded into Q at the QKV-GEMM epilogue

union HU { _Float16 h; US u; };
__device__ __forceinline__ US f2h(float f){ HU x; x.h = (_Float16)f; return x.u; }
__device__ __forceinline__ unsigned pkrtz(float a, float b){
  union { fp16x2 h; unsigned u; } x;
  x.h = __builtin_amdgcn_cvt_pkrtz(a, b);
  return x.u;
}

union U8 { US u[8]; uint4 v; };
union U4 { US u[4]; uint2 v; };
union UPA { unsigned u[2]; h16x4 h; };

// async global->LDS, 16B/lane; LDS dest = wave-uniform base + lane*16 (no padding possible)
__device__ __forceinline__ void glds16(const US* g, US* l){
  __builtin_amdgcn_global_load_lds(
    (const __attribute__((address_space(1))) unsigned int*)(const void*)g,
    (__attribute__((address_space(3))) unsigned int*)(void*)l, 16, 0, 0);
}

// ---- fused convert: x (2048 blocks) + Wq/Wk/Wv/Wo (512 blocks each) fp32->fp16 ----
__global__ __launch_bounds__(256) void conv_all(
    const float* __restrict__ x,
    const float* __restrict__ w0, const float* __restrict__ w1,
    const float* __restrict__ w2, const float* __restrict__ w3,
    US* __restrict__ xh, US* __restrict__ Wall)
{
  const int id = blockIdx.x;
  const float* s; US* d; size_t off;
  if (id < 2048) { s = x; d = xh; off = (size_t)id*2048; }
  else {
    int j = id - 2048, wsel = j>>9;
    off = (size_t)(j&511)*2048;
    s = (wsel==0)?w0:(wsel==1)?w1:(wsel==2)?w2:w3;
    d = Wall + (size_t)wsel*1048576;
  }
  size_t i = off + (size_t)threadIdx.x*8;
  float f[8];
  *(float4*)&f[0] = *(const float4*)&s[i];
  *(float4*)&f[4] = *(const float4*)&s[i+4];
  U8 h;
  #pragma unroll
  for (int j=0;j<8;++j) h.u[j] = f2h(f[j]);
  *(uint4*)&d[i] = h.v;
}

// ---- QKV GEMM, m97 geometry: 128x128 tile, BK=32, z-sliced (z selects Wq/Wk/Wv).
// Grid (8,32,3) = 768 blocks = exactly 3 blocks/CU at (256,3) -> single occupancy round.
// Outputs: z=0 Q*SCL fp16 [B,H,N,D]; z=1 K fp16 [B,H,N,D]; z=2 V fp16 [B,H,D,N] (transposed).
__global__ __launch_bounds__(256,3) void qkv_gemm(
    const US* __restrict__ A, const US* __restrict__ Wall,
    const float* __restrict__ bq, const float* __restrict__ bk, const float* __restrict__ bv,
    US* __restrict__ Qf, US* __restrict__ Kf, US* __restrict__ Vtb)
{
  __shared__ __align__(16) US sA[128*32];
  __shared__ __align__(16) US sW[128*32];
  const int z = blockIdx.z;
  const US* W = Wall + (size_t)z*1048576;
  const float* bias = (z==0)?bq:(z==1)?bk:bv;

  const int t = threadIdx.x;
  const int w = t>>6, lane = t&63;
  const int q = lane>>4, c = lane&15;
  const int mq = (w>>1)*64, nq = (w&1)*64;
  const int gm0 = blockIdx.y*128, gn0 = blockIdx.x*128;
  const int r16 = lane>>2, seg = lane&3;    // staging: 4 lanes/row, 16B each

  f32x4 acc[4][4] = {};
  for (int kb = 0; kb < 1024; kb += 32) {
    #pragma unroll
    for (int p=0;p<2;++p){
      int rb = (w*2+p)*16;
      glds16(&A[(size_t)(gm0 + rb + r16)*1024 + kb + seg*8], &sA[rb*32]);
      glds16(&W[(size_t)(gn0 + rb + r16)*1024 + kb + seg*8], &sW[rb*32]);
    }
    __syncthreads();
    h16x8 af[4], wf[4];
    #pragma unroll
    for (int rt=0;rt<4;++rt) af[rt] = *(const h16x8*)&sA[(mq+rt*16+c)*32 + q*8];
    #pragma unroll
    for (int ct=0;ct<4;++ct) wf[ct] = *(const h16x8*)&sW[(nq+ct*16+c)*32 + q*8];
    #pragma unroll
    for (int rt=0;rt<4;++rt)
      #pragma unroll
      for (int ct=0;ct<4;++ct)
        acc[rt][ct] = MFMA16F(af[rt], wf[ct], acc[rt][ct]);
    __syncthreads();
  }
  #pragma unroll
  for (int rt=0;rt<4;++rt)
  #pragma unroll
  for (int ct=0;ct<4;++ct) {
    int col = gn0 + nq + ct*16 + c;
    float bv_ = bias[col];
    int rowb = gm0 + mq + rt*16 + q*4;
    int hh = col>>6, d = col & 63;
    if (z==2) {
      int b = rowb>>11, n = rowb & (N_-1);
      U4 pk;
      #pragma unroll
      for (int r=0;r<4;++r) pk.u[r] = f2h(acc[rt][ct][r] + bv_);
      *(uint2*)&Vtb[((size_t)(b*H_+hh)*D_ + d)*N_ + n] = pk.v;
    } else {
      US* dst = (z==0) ? Qf : Kf;
      #pragma unroll
      for (int r=0;r<4;++r) {
        int row = rowb + r;
        float v = acc[rt][ct][r] + bv_;
        if (z==0) v *= SCL;      // fold softmax scale + log2e into Q (fp32, pre-rounding)
        int b = row>>11, n = row & (N_-1);
        dst[((size_t)(b*H_+hh)*N_+n)*D_ + d] = f2h(v);
      }
    }
  }
}

// ---- O GEMM: out = H @ Wo^T + bo, fp32 row-major [4096][1024].
// R13: 64x64 tiles, grid (16,64)=1024 blocks, (256,8) -> VGPR<=64 -> 4 blocks/CU
// = 16 waves/CU (was 2 blocks x 4 waves = 8 waves/CU at 128x64: latency-starved).
__global__ __launch_bounds__(256,8) void o_gemm(
    const US* __restrict__ A, const US* __restrict__ W,
    const float* __restrict__ bias, float* __restrict__ out)
{
  __shared__ __align__(16) US sA[64*32];
  __shared__ __align__(16) US sW[64*32];
  const int t = threadIdx.x;
  const int w = t>>6, lane = t&63;
  const int q = lane>>4, c = lane&15;
  const int wr = (w>>1)*32, wc = (w&1)*32;
  const int gm0 = blockIdx.y*64, gn0 = blockIdx.x*64;
  const int r4 = lane>>2, seg = lane&3;   // per wave: 16 rows x 4 chunks of 16B

  f32x4 acc[2][2] = {};
  for (int kb = 0; kb < 1024; kb += 32) {
    glds16(&A[(size_t)(gm0 + w*16 + r4)*1024 + kb + seg*8], &sA[(w*16)*32]);
    glds16(&W[(size_t)(gn0 + w*16 + r4)*1024 + kb + seg*8], &sW[(w*16)*32]);
    __syncthreads();
    h16x8 af[2], wf[2];
    #pragma unroll
    for (int rt=0;rt<2;++rt) af[rt] = *(const h16x8*)&sA[(wr+rt*16+c)*32 + q*8];
    #pragma unroll
    for (int ct=0;ct<2;++ct) wf[ct] = *(const h16x8*)&sW[(wc+ct*16+c)*32 + q*8];
    #pragma unroll
    for (int rt=0;rt<2;++rt)
      #pragma unroll
      for (int ct=0;ct<2;++ct)
        acc[rt][ct] = MFMA16F(af[rt], wf[ct], acc[rt][ct]);
    __syncthreads();
  }
  #pragma unroll
  for (int rt=0; rt<2; ++rt)
  #pragma unroll
  for (int ct=0; ct<2; ++ct) {
    int col = gn0 + wc + ct*16 + c;
    float bv_ = bias[col];
    int rowb = gm0 + wr + rt*16 + q*4;
    #pragma unroll
    for (int r=0;r<4;++r)
      out[(size_t)(rowb+r)*1024 + col] = acc[rt][ct][r] + bv_;
  }
}

// ---- Flash attention (R11 structure, best measured, + defer-max + max3 grouping).
// 512-thread blocks (8 waves), transposed-S, 128-key tiles; wave owns 16 q-rows.
// Register-P PV via K=16 v_mfma_f32_16x16x16f16 (A-frag key layout 4q+j == S^T
// C-layout -> P never touches LDS). Double-buffered K/V in LDS (71.7 KB, 2 blocks/CU
// grid-capped). T14 reg-staged: global->reg at loop top (full tile compute covers
// latency), ds_write into buf^1 at bottom, ONE barrier per iteration.
// Defer-max THR=8 (exp2 domain; P <= 2^8 fp16-safe; proven same absmax in R12).
// R12 lessons: glds-at-top+early-barrier loses cover (-8us); V XOR-swizzle reads are
// 2x worse than padded VSTR=136 (which is conflict-free minimum for b64).
#define KSTR2 72   // K tile row stride
#define VSTR  136  // Vt row stride (128 keys + 8)
__global__ __launch_bounds__(512,4) void attn(
    const US* __restrict__ Qf, const US* __restrict__ Kf, const US* __restrict__ Vt,
    US* __restrict__ Hout)
{
  __shared__ __align__(16) US sK [2][128*KSTR2];
  __shared__ __align__(16) US sVt[2][64*VSTR];
  const int t = threadIdx.x;
  const int w = t>>6, lane = t&63, q = lane>>4, c = lane&15;
  const int id = blockIdx.x;
  // XCD swizzle: 16 q-tiles of one (b,h) stay on one XCD (id%8 stable across them)
  const int bh = ((id & 7) << 2) | ((id >> 3) & 3);
  const int n0 = (id >> 5) * 128;
  const US* Kp = Kf + (size_t)bh * (N_*D_);
  const US* Vp = Vt + (size_t)bh * (D_*N_);

  // Q B-frags in registers (pre-scaled): rows n0 + w*16 + c
  const size_t qoff = (size_t)bh*(N_*D_) + (size_t)(n0 + w*16 + c)*D_;
  h16x8 qb0 = *(const h16x8*)&Qf[qoff + q*8];
  h16x8 qb1 = *(const h16x8*)&Qf[qoff + 32 + q*8];
  h16x4 vones;
  #pragma unroll
  for (int j=0;j<4;++j) vones[j] = (_Float16)1.0f;

  float mi = -INFINITY;
  f32x4 o[5] = {};           // 0..3 = output d-cols; 4 = l accumulator (ones-row)

  const int kr = t>>3, kc8 = (t&7)*8;     // K staging: 8 thr/row, 64 rows/pass
  const int vr = t>>4, vc8 = (t&15)*8;    // Vt staging: 16 thr/row, 32 rows/pass

  // prologue: stage tile 0 into buffer 0
  #pragma unroll
  for (int p=0;p<2;++p){
    int r = p*64 + kr;
    *(uint4*)&sK[0][r*KSTR2 + kc8] = *(const uint4*)&Kp[(size_t)r*D_ + kc8];
  }
  #pragma unroll
  for (int p=0;p<2;++p){
    int r = p*32 + vr;
    *(uint4*)&sVt[0][r*VSTR + vc8] = *(const uint4*)&Vp[(size_t)r*N_ + vc8];
  }
  __syncthreads();

  for (int mt=0; mt<16; ++mt) {
    const int cur = mt&1;
    // T14 issue-early: next tile's global loads into regs; vmcnt waited only at the
    // ds_write at the bottom -- QK+softmax+PV covers the latency.
    uint4 kreg[2], vreg[2];
    if (mt < 15){
      const int m1 = (mt+1)*128;
      #pragma unroll
      for (int p=0;p<2;++p)
        kreg[p] = *(const uint4*)&Kp[(size_t)(m1 + p*64 + kr)*D_ + kc8];
      #pragma unroll
      for (int p=0;p<2;++p)
        vreg[p] = *(const uint4*)&Vp[(size_t)(p*32 + vr)*N_ + m1 + vc8];
    }

    // S^T: key f-frags (A=K rows f*16+c), qrow = B-col; already in exp2 domain
    f32x4 s[8];
    __builtin_amdgcn_s_setprio(1);
    #pragma unroll
    for (int f=0; f<8; ++f){
      h16x8 k0 = *(const h16x8*)&sK[cur][(f*16+c)*KSTR2 + q*8];
      h16x8 k1 = *(const h16x8*)&sK[cur][(f*16+c)*KSTR2 + 32 + q*8];
      f32x4 sv = {};
      sv = MFMA16F(k0, qb0, sv);
      sv = MFMA16F(k1, qb1, sv);
      s[f] = sv;
    }
    __builtin_amdgcn_s_setprio(0);

    // softmax: keys lane-local (32/lane); this lane's qrow = c. max3-friendly tree.
    f32x4 t1;
    #pragma unroll
    for (int j=0;j<4;++j){
      float a = fmaxf(fmaxf(s[0][j],s[1][j]),s[2][j]);
      float b = fmaxf(fmaxf(s[3][j],s[4][j]),s[5][j]);
      float d = fmaxf(fmaxf(s[6][j],s[7][j]),a);
      t1[j] = fmaxf(b,d);
    }
    float v = fmaxf(fmaxf(t1[0],t1[1]), fmaxf(t1[2],t1[3]));
    v = fmaxf(v, __shfl_xor(v, 16));
    v = fmaxf(v, __shfl_xor(v, 32));     // replicated across the 4 q-lanes
    // defer-max THR=8: rescale only when some row exceeds mi by >8 (P <= 2^8 fp16-safe)
    if (!__all(v <= mi + 8.0f)) {
      float mnew = fmaxf(mi, v);
      float alpha = exp2f(mi - mnew);
      float ar[4];
      #pragma unroll
      for (int r=0; r<4; ++r) ar[r] = __shfl(alpha, q*4+r);
      #pragma unroll
      for (int dt=0; dt<5; ++dt){        // includes the l accumulator
        o[dt][0]*=ar[0]; o[dt][1]*=ar[1]; o[dt][2]*=ar[2]; o[dt][3]*=ar[3];
      }
      mi = mnew;
    }
    // exp2 + pack P (rtz); P feeds PV directly as K=16 A-frags (keys 4q+j match the
    // S^T C-layout) -- no LDS round-trip. l comes from the ones-column MFMA.
    #pragma unroll
    for (int f=0; f<8; ++f){
      float p0 = exp2f(s[f][0]-mi);
      float p1 = exp2f(s[f][1]-mi);
      float p2 = exp2f(s[f][2]-mi);
      float p3 = exp2f(s[f][3]-mi);
      UPA pa;
      pa.u[0] = pkrtz(p0, p1);
      pa.u[1] = pkrtz(p2, p3);
      h16x4 pah = pa.h;
      __builtin_amdgcn_s_setprio(1);
      #pragma unroll
      for (int dt=0; dt<4; ++dt){
        h16x4 vf = *(const h16x4*)&sVt[cur][(dt*16+c)*VSTR + f*16 + q*4];
        o[dt] = MFMA161(pah, vf, o[dt]);
      }
      o[4] = MFMA161(pah, vones, o[4]);
      __builtin_amdgcn_s_setprio(0);
    }

    // T14 write-late: land next tile in buf^1 (last read in iter mt-1; its trailing
    // barrier already fenced it -- no extra barrier needed before these writes).
    if (mt < 15){
      #pragma unroll
      for (int p=0;p<2;++p)
        *(uint4*)&sK[cur^1][(p*64+kr)*KSTR2 + kc8] = kreg[p];
      #pragma unroll
      for (int p=0;p<2;++p)
        *(uint4*)&sVt[cur^1][(p*32+vr)*VSTR + vc8] = vreg[p];
    }
    __syncthreads();
  }

  // l is row-indexed (component r = row q*4+r): no shfl needed
  const int b = bh>>4, hh = bh&15;
  float ir[4];
  #pragma unroll
  for (int r=0; r<4; ++r) ir[r] = 1.0f / o[4][r];
  #pragma unroll
  for (int dt=0; dt<4; ++dt){
    #pragma unroll
    for (int r=0; r<4; ++r){
      int n = n0 + w*16 + q*4 + r;
      int d = dt*16 + c;
      Hout[((size_t)(b*N_+n)*H_+hh)*D_ + d] = f2h(o[dt][r] * ir[r]);  // [B,N,E] fp16
    }
  }
}

extern "C" void kernel_launch(void* const* d_in, const int* in_sizes, int n_in,
                              void* d_out, int out_size, void* d_ws, size_t ws_size,
                              hipStream_t stream)
{
  const float* x  = (const float*)d_in[0];
  const float* Wq = (const float*)d_in[1];
  const float* bq = (const float*)d_in[2];
  const float* Wk = (const float*)d_in[3];
  const float* bk = (const float*)d_in[4];
  const float* Wv = (const float*)d_in[5];
  const float* bv = (const float*)d_in[6];
  const float* Wo = (const float*)d_in[7];
  const float* bo = (const float*)d_in[8];
  US* ws  = (US*)d_ws;
  const size_t M1 = 1048576;
  US* xh   = ws;                 // 4M fp16
  US* Wall = ws + 4*M1;          // 4M: Wq,Wk,Wv,Wo fp16 contiguous
  US* Qf   = ws + 8*M1;          // 4M, [B,H,N,D], pre-scaled by 8*log2e
  US* Kf   = ws + 12*M1;         // 4M, [B,H,N,D]
  US* Vtb  = ws + 16*M1;         // 4M, [B,H,D,N]
  US* Hf   = ws + 20*M1;         // 4M, [B,N,E]  -> 48 MB total

  conv_all<<<4096, 256, 0, stream>>>(x, Wq, Wk, Wv, Wo, xh, Wall);
  qkv_gemm<<<dim3(8,32,3), 256, 0, stream>>>(xh, Wall, bq, bk, bv, Qf, Kf, Vtb);
  attn<<<512, 512, 0, stream>>>(Qf, Kf, Vtb, Hf);
  o_gemm<<<dim3(16,64), 256, 0, stream>>>(Hf, Wall + 3*M1, bo, (float*)d_out);
}